// Round 4
// baseline (4568.035 us; speedup 1.0000x reference)
//
#include <hip/hip_runtime.h>

#define N_USERS 100000
#define N_ITEMS 200000
#define N_NODES (N_USERS + N_ITEMS)
#define EMB     64
#define NNZ     4000000

#define BSHIFT  8
#define BROWS   (1 << BSHIFT)                              // 256 rows / bucket
#define NB      ((N_NODES + BROWS - 1) >> BSHIFT)          // 1172 buckets

#define EPB     16384                                      // edges per sort block
#define NBLK    ((NNZ + EPB - 1) / EPB)                    // 245
#define NS      (NB * NBLK)                                // 287140 counts

#define SCAN_BLOCK 256
#define SCAN_ITEMS 4
#define SCAN_TILE  (SCAN_BLOCK * SCAN_ITEMS)               // 1024
#define ST1        ((NS + SCAN_TILE - 1) / SCAN_TILE)      // 281 tiles (<=512)

// ===========================================================================
// Phase A: counting sort of edges into 256-row buckets
// ===========================================================================

// A1: per-block bucket histogram -> count[bucket*NBLK + blk]
__global__ void a1_hist(const int* __restrict__ rows, int* __restrict__ count) {
    __shared__ int hist[NB];
    for (int i = threadIdx.x; i < NB; i += blockDim.x) hist[i] = 0;
    __syncthreads();
    int base = blockIdx.x * EPB;
    int lim  = NNZ - base; if (lim > EPB) lim = EPB;
    for (int i = threadIdx.x; i < lim; i += blockDim.x)
        atomicAdd(&hist[rows[base + i] >> BSHIFT], 1);
    __syncthreads();
    for (int b = threadIdx.x; b < NB; b += blockDim.x)
        count[b * NBLK + blockIdx.x] = hist[b];
}

// generic hierarchical exclusive scan (in-place safe: each idx owned by one thread)
__global__ void scan1_kernel(int* __restrict__ data, int* __restrict__ tile_sums, int n) {
    __shared__ int s[SCAN_BLOCK];
    int tid  = threadIdx.x;
    int base = blockIdx.x * SCAN_TILE + tid * SCAN_ITEMS;
    int v[SCAN_ITEMS];
    int sum = 0;
#pragma unroll
    for (int j = 0; j < SCAN_ITEMS; j++) {
        int idx = base + j;
        v[j] = (idx < n) ? data[idx] : 0;
        sum += v[j];
    }
    s[tid] = sum;
    __syncthreads();
    for (int off = 1; off < SCAN_BLOCK; off <<= 1) {
        int t = 0;
        if (tid >= off) t = s[tid - off];
        __syncthreads();
        if (tid >= off) s[tid] += t;
        __syncthreads();
    }
    int run = s[tid] - sum;
#pragma unroll
    for (int j = 0; j < SCAN_ITEMS; j++) {
        int idx = base + j;
        if (idx < n) data[idx] = run;
        run += v[j];
    }
    if (tid == SCAN_BLOCK - 1) tile_sums[blockIdx.x] = s[tid];
}

__global__ void scan2_kernel(int* __restrict__ tile_sums, int nt) {
    __shared__ int s[512];
    int tid = threadIdx.x;
    int v = (tid < nt) ? tile_sums[tid] : 0;
    s[tid] = v;
    __syncthreads();
    for (int off = 1; off < 512; off <<= 1) {
        int t = 0;
        if (tid >= off) t = s[tid - off];
        __syncthreads();
        if (tid >= off) s[tid] += t;
        __syncthreads();
    }
    if (tid < nt) tile_sums[tid] = s[tid] - v;
}

__global__ void scan3_kernel(int* __restrict__ data, const int* __restrict__ tile_sums, int n) {
    int i = blockIdx.x * blockDim.x + threadIdx.x;
    if (i < n) data[i] += tile_sums[i / SCAN_TILE];
}

// bucket_ptr[b] = first edge of bucket b
__global__ void bptr_kernel(const int* __restrict__ offset, int* __restrict__ bptr) {
    int b = blockIdx.x * blockDim.x + threadIdx.x;
    if (b < NB) bptr[b] = offset[b * NBLK];
    if (b == 0) bptr[NB] = NNZ;
}

// A2: scatter edges to bucket-grouped order. Each (block,bucket) destination
// range is contiguous and written by exactly ONE block (one CU/XCD) -> lines
// fill inside a single L2 before writeback.
// payload: .x = val bits, .y = (rlo<<24) | col   (col < 2^24, rlo < 256)
__global__ void a2_scatter(const int*   __restrict__ rows,
                           const int*   __restrict__ cols,
                           const float* __restrict__ vals,
                           const int*   __restrict__ offset,
                           uint2*       __restrict__ pay) {
    __shared__ int cur[NB];
    for (int b = threadIdx.x; b < NB; b += blockDim.x)
        cur[b] = offset[b * NBLK + blockIdx.x];
    __syncthreads();
    int base = blockIdx.x * EPB;
    int lim  = NNZ - base; if (lim > EPB) lim = EPB;
    for (int i = threadIdx.x; i < lim; i += blockDim.x) {
        int e = base + i;
        int r = rows[e];
        int b = r >> BSHIFT;
        int pos = atomicAdd(&cur[b], 1);
        pay[pos] = make_uint2((unsigned)__float_as_int(vals[e]),
                              ((unsigned)(r & (BROWS - 1)) << 24) | (unsigned)cols[e]);
    }
}

// ===========================================================================
// init: out = bufA = concat(user, item)
// ===========================================================================
__global__ void init2_kernel(const float* __restrict__ user_t,
                             const float* __restrict__ item_t,
                             float* __restrict__ out,
                             float* __restrict__ bufA) {
    int i = blockIdx.x * blockDim.x + threadIdx.x;
    const int total4 = N_NODES * EMB / 4;
    if (i >= total4) return;
    int fi   = i * 4;
    int node = fi >> 6;
    int off  = fi & 63;
    float4 v;
    if (node < N_USERS)
        v = *(const float4*)(user_t + (size_t)node * EMB + off);
    else
        v = *(const float4*)(item_t + (size_t)(node - N_USERS) * EMB + off);
    *(float4*)(out  + fi) = v;
    *(float4*)(bufA + fi) = v;
}

// ===========================================================================
// SpMM: one block per bucket; 64 KB LDS accumulator (256 rows x 64 dims).
// Edge broadcast via v_readlane (j uniform) -> col wave-uniform -> coalesced
// 256B gather; ds_add_f32 addr = rlo*64+lane -> 2 lanes/bank (free).
// ===========================================================================
__global__ void __launch_bounds__(256) spmm_lds(const int*   __restrict__ bptr,
                                                const uint2* __restrict__ pay,
                                                const float* __restrict__ x,
                                                float*       __restrict__ y,
                                                float*       __restrict__ out,
                                                float scale, int write_y) {
    __shared__ float acc[BROWS * EMB];          // 64 KB
    int tid = threadIdx.x;
    float4* acc4 = (float4*)acc;
    for (int i = tid; i < BROWS * EMB / 4; i += 256)
        acc4[i] = make_float4(0.f, 0.f, 0.f, 0.f);
    __syncthreads();

    int b    = blockIdx.x;
    int beg  = bptr[b];
    int end  = bptr[b + 1];
    int lane = tid & 63;
    int wid  = tid >> 6;

    for (int chunk = beg + wid * 64; chunk < end; chunk += 256) {
        int idx = chunk + lane;
        uint2 p = (idx < end) ? pay[idx] : make_uint2(0u, 0u);
        int n = end - chunk; if (n > 64) n = 64;
        if (n == 64) {
#pragma unroll 4
            for (int j = 0; j < 64; j++) {
                unsigned lo = (unsigned)__builtin_amdgcn_readlane((int)p.x, j);
                unsigned hi = (unsigned)__builtin_amdgcn_readlane((int)p.y, j);
                float v  = __uint_as_float(lo);
                int col  = (int)(hi & 0xFFFFFFu);
                int rlo  = (int)(hi >> 24);
                float xv = x[((size_t)col << 6) + lane];
                atomicAdd(&acc[(rlo << 6) + lane], v * xv);
            }
        } else {
            for (int j = 0; j < n; j++) {
                unsigned lo = (unsigned)__builtin_amdgcn_readlane((int)p.x, j);
                unsigned hi = (unsigned)__builtin_amdgcn_readlane((int)p.y, j);
                float v  = __uint_as_float(lo);
                int col  = (int)(hi & 0xFFFFFFu);
                int rlo  = (int)(hi >> 24);
                float xv = x[((size_t)col << 6) + lane];
                atomicAdd(&acc[(rlo << 6) + lane], v * xv);
            }
        }
    }
    __syncthreads();

    // write out: rows r0 .. r0+nrows-1, contiguous 64 KB
    int r0 = b << BSHIFT;
    int nrows = N_NODES - r0; if (nrows > BROWS) nrows = BROWS;
    int nf4 = nrows * EMB / 4;
    size_t gbase = (size_t)r0 * (EMB / 4);     // float4 index
    float4* y4 = (float4*)y;
    float4* o4 = (float4*)out;
    for (int i = tid; i < nf4; i += 256) {
        float4 a = acc4[i];
        if (write_y) y4[gbase + i] = a;
        float4 o = o4[gbase + i];
        o.x = (o.x + a.x) * scale;
        o.y = (o.y + a.y) * scale;
        o.z = (o.z + a.z) * scale;
        o.w = (o.w + a.w) * scale;
        o4[gbase + i] = o;
    }
}

// ===========================================================================
// Fallback atomic path (tiny ws only)
// ===========================================================================
__global__ void init_kernel(const float* __restrict__ user_t,
                            const float* __restrict__ item_t,
                            float* __restrict__ out,
                            float* __restrict__ bufA,
                            float* __restrict__ bufB) {
    int i = blockIdx.x * blockDim.x + threadIdx.x;
    const int total4 = N_NODES * EMB / 4;
    if (i >= total4) return;
    int fi   = i * 4;
    int node = fi >> 6;
    int off  = fi & 63;
    float4 v;
    if (node < N_USERS)
        v = *(const float4*)(user_t + (size_t)node * EMB + off);
    else
        v = *(const float4*)(item_t + (size_t)(node - N_USERS) * EMB + off);
    *(float4*)(out  + fi) = v;
    *(float4*)(bufA + fi) = v;
    *(float4*)(bufB + fi) = make_float4(0.f, 0.f, 0.f, 0.f);
}

__global__ void spmm_kernel(const int*   __restrict__ rows,
                            const int*   __restrict__ cols,
                            const float* __restrict__ vals,
                            const float* __restrict__ x,
                            float*       __restrict__ y) {
    int tid  = blockIdx.x * blockDim.x + threadIdx.x;
    int e    = tid >> 6;
    int lane = tid & 63;
    if (e >= NNZ) return;
    atomicAdd(&y[(size_t)rows[e] * EMB + lane], vals[e] * x[(size_t)cols[e] * EMB + lane]);
}

__global__ void acc_zero_kernel(float* __restrict__ out,
                                const float* __restrict__ src,
                                float* __restrict__ zbuf) {
    int i = blockIdx.x * blockDim.x + threadIdx.x;
    const int total4 = N_NODES * EMB / 4;
    if (i >= total4) return;
    int fi = i * 4;
    float4 o = *(float4*)(out + fi);
    float4 s = *(const float4*)(src + fi);
    o.x += s.x; o.y += s.y; o.z += s.z; o.w += s.w;
    *(float4*)(out  + fi) = o;
    *(float4*)(zbuf + fi) = make_float4(0.f, 0.f, 0.f, 0.f);
}

__global__ void final_kernel(float* __restrict__ out,
                             const float* __restrict__ src) {
    int i = blockIdx.x * blockDim.x + threadIdx.x;
    const int total4 = N_NODES * EMB / 4;
    if (i >= total4) return;
    int fi = i * 4;
    float4 o = *(float4*)(out + fi);
    float4 s = *(const float4*)(src + fi);
    o.x = (o.x + s.x) * 0.25f;
    o.y = (o.y + s.y) * 0.25f;
    o.z = (o.z + s.z) * 0.25f;
    o.w = (o.w + s.w) * 0.25f;
    *(float4*)(out + fi) = o;
}

// ===========================================================================
extern "C" void kernel_launch(void* const* d_in, const int* in_sizes, int n_in,
                              void* d_out, int out_size, void* d_ws, size_t ws_size,
                              hipStream_t stream) {
    const float* user_t = (const float*)d_in[0];
    const float* item_t = (const float*)d_in[1];
    const int*   rows   = (const int*)d_in[2];
    const int*   cols   = (const int*)d_in[3];
    const float* vals   = (const float*)d_in[4];
    float* out = (float*)d_out;

    const size_t emb_elems = (size_t)N_NODES * EMB;
    const int total4    = N_NODES * EMB / 4;
    const int ew_blocks = (total4 + 255) / 256;

    // ---- workspace layout ----
    char* p = (char*)d_ws;
    float*  bufA      = (float*)p;  p += emb_elems * 4;            // 76.8 MB
    float*  bufB      = (float*)p;  p += emb_elems * 4;            // 76.8 MB
    uint2*  pay       = (uint2*)p;  p += (size_t)NNZ * 8;          // 32 MB
    int*    count     = (int*)p;    p += (size_t)NS * 4;           // 1.15 MB
    int*    tile_sums = (int*)p;    p += (size_t)ST1 * 4;
    int*    bptr      = (int*)p;    p += (size_t)(NB + 1) * 4;
    size_t need = (size_t)(p - (char*)d_ws);

    if (ws_size >= need) {
        // ---- counting sort into buckets ----
        a1_hist     <<<NBLK, 256, 0, stream>>>(rows, count);
        scan1_kernel<<<ST1, SCAN_BLOCK, 0, stream>>>(count, tile_sums, NS);
        scan2_kernel<<<1, 512, 0, stream>>>(tile_sums, ST1);
        scan3_kernel<<<(NS + 255) / 256, 256, 0, stream>>>(count, tile_sums, NS);
        bptr_kernel <<<(NB + 255) / 256, 256, 0, stream>>>(count, bptr);
        a2_scatter  <<<NBLK, 256, 0, stream>>>(rows, cols, vals, count, pay);

        // ---- init + 3 fused LDS-accumulated SpMM layers ----
        init2_kernel<<<ew_blocks, 256, 0, stream>>>(user_t, item_t, out, bufA);
        spmm_lds<<<NB, 256, 0, stream>>>(bptr, pay, bufA, bufB, out, 1.0f, 1);
        spmm_lds<<<NB, 256, 0, stream>>>(bptr, pay, bufB, bufA, out, 1.0f, 1);
        spmm_lds<<<NB, 256, 0, stream>>>(bptr, pay, bufA, bufB, out, 0.25f, 0);
    } else {
        // ---- fallback: atomic path ----
        const int spmm_blocks = (int)(((size_t)NNZ * 64 + 255) / 256);
        init_kernel<<<ew_blocks, 256, 0, stream>>>(user_t, item_t, out, bufA, bufB);
        spmm_kernel<<<spmm_blocks, 256, 0, stream>>>(rows, cols, vals, bufA, bufB);
        acc_zero_kernel<<<ew_blocks, 256, 0, stream>>>(out, bufB, bufA);
        spmm_kernel<<<spmm_blocks, 256, 0, stream>>>(rows, cols, vals, bufB, bufA);
        acc_zero_kernel<<<ew_blocks, 256, 0, stream>>>(out, bufA, bufB);
        spmm_kernel<<<spmm_blocks, 256, 0, stream>>>(rows, cols, vals, bufA, bufB);
        final_kernel<<<ew_blocks, 256, 0, stream>>>(out, bufB);
    }
}